// Round 4
// baseline (409.061 us; speedup 1.0000x reference)
//
#include <hip/hip_runtime.h>

typedef short  s16x8 __attribute__((ext_vector_type(8)));
typedef float  f32x4 __attribute__((ext_vector_type(4)));
typedef unsigned short u16x4 __attribute__((ext_vector_type(4)));

// ---------------- workspace layout (bytes) ----------------
#define AH_OFF    0ULL
#define AL_OFF    50331648ULL
#define APH_OFF   100663296ULL
#define APL_OFF   119537664ULL
#define BH_OFF    138412032ULL
#define BL_OFF    139067392ULL
#define BPH_OFF   139722752ULL
#define BPL_OFF   140460032ULL
#define HEAD_OFF  141197312ULL
#define PROP_OFF  151027712ULL   // total 160,858,112

// ---------- fp32 -> bf16 hi/lo split (RNE both) ----------
__device__ __forceinline__ void split2(float x, unsigned short& h, unsigned short& l) {
    unsigned u  = __float_as_uint(x);
    unsigned hb = (u + 0x7FFFu + ((u >> 16) & 1u)) >> 16;
    float hf = __uint_as_float(hb << 16);
    float lf = x - hf;
    unsigned ul = __float_as_uint(lf);
    unsigned lb = (ul + 0x7FFFu + ((ul >> 16) & 1u)) >> 16;
    h = (unsigned short)hb; l = (unsigned short)lb;
}

// nontemporal split-store: keep streaming A-panel writes out of L3 so emb stays resident
__device__ __forceinline__ void split_store4_nt(unsigned short* ph, unsigned short* pl, float4 f) {
    u16x4 h, l;
    split2(f.x, ((unsigned short*)&h)[0], ((unsigned short*)&l)[0]);
    split2(f.y, ((unsigned short*)&h)[1], ((unsigned short*)&l)[1]);
    split2(f.z, ((unsigned short*)&h)[2], ((unsigned short*)&l)[2]);
    split2(f.w, ((unsigned short*)&h)[3], ((unsigned short*)&l)[3]);
    __builtin_nontemporal_store(h, (u16x4*)ph);
    __builtin_nontemporal_store(l, (u16x4*)pl);
}

__device__ __forceinline__ void gload16(const unsigned short* g, unsigned short* l) {
    __builtin_amdgcn_global_load_lds(
        (const __attribute__((address_space(1))) unsigned int*)g,
        (__attribute__((address_space(3))) unsigned int*)l, 16, 0, 0);
}

// =============================================================
// Kernel A: gather + online-softmax attention.
// Deferred rescale (THR=8) + 4-deep row software pipeline
// (fully unrolled so slot indices are compile-time constants).
// one wave per (head h in [0,6), b in [0,4096))
// =============================================================
__global__ __launch_bounds__(256) void attend_kernel(
    const int* __restrict__ inputs,        // (4096,2,32)
    const int* __restrict__ inputs_prop,   // (4096,2,3,32)
    const float* __restrict__ emb,         // (100000,512)
    const float* __restrict__ v,           // (31,)
    unsigned short* __restrict__ Ah, unsigned short* __restrict__ Al,
    unsigned short* __restrict__ Aph, unsigned short* __restrict__ Apl)
{
    int w    = blockIdx.x * 4 + (threadIdx.x >> 6);
    int lane = threadIdx.x & 63;
    int h = w >> 12;         // 0..5
    int b = w & 4095;

    int base, i = 0;
    const int* ip;
    if (h < 2) { base = (b * 2 + h) * 32; ip = inputs; }
    else {
        i = (h - 2) >> 1;
        int s = 1 + ((h - 2) & 1);
        base = ((b * 2 + i) * 3 + s) * 32;
        ip = inputs_prop;
    }

    int myidx = 0;
    if (lane < 32) myidx = ip[base + lane];
    int idx0 = __shfl(myidx, 0);

    const float4* emb4 = (const float4*)emb;
    float4 n0 = emb4[(size_t)idx0 * 128 + lane];
    float4 n1 = emb4[(size_t)idx0 * 128 + 64 + lane];

    // 4-deep pipeline: preload rows j=1..4 into slots 0..3
    float4 pa[4], pb[4];
    #pragma unroll
    for (int j = 1; j <= 4; ++j) {
        int ij = __shfl(myidx, j);
        pa[(j - 1) & 3] = emb4[(size_t)ij * 128 + lane];
        pb[(j - 1) & 3] = emb4[(size_t)ij * 128 + 64 + lane];
    }

    float m = -3.0e38f, den = 0.0f;
    float4 c0 = make_float4(0.f, 0.f, 0.f, 0.f);
    float4 c1 = make_float4(0.f, 0.f, 0.f, 0.f);

    #pragma unroll
    for (int j = 1; j < 32; ++j) {
        const int slot = (j - 1) & 3;
        float4 e0 = pa[slot];
        float4 e1 = pb[slot];
        if (j + 4 < 32) {                     // refill slot with row j+4
            int ijn = __shfl(myidx, j + 4);
            pa[slot] = emb4[(size_t)ijn * 128 + lane];
            pb[slot] = emb4[(size_t)ijn * 128 + 64 + lane];
        }
        float p = e0.x * n0.x + e0.y * n0.y + e0.z * n0.z + e0.w * n0.w
                + e1.x * n1.x + e1.y * n1.y + e1.z * n1.z + e1.w * n1.w;
        #pragma unroll
        for (int d = 1; d < 64; d <<= 1) p += __shfl_xor(p, d);

        float s = (p != 0.0f) ? p : -9999.0f;   // mask: scores==0 -> -NEG
        if (s - m > 8.0f) {                     // rare, wave-uniform rescale
            float scale = __expf(m - s);        // m=-3e38 -> 0 on first hit
            den *= scale;
            c0.x *= scale; c0.y *= scale; c0.z *= scale; c0.w *= scale;
            c1.x *= scale; c1.y *= scale; c1.z *= scale; c1.w *= scale;
            m = s;
        }
        float e = __expf(s - m);                // bounded by e^8
        den += e;
        float we = v[j - 1] * e;
        c0.x += we * e0.x;  c0.y += we * e0.y;  c0.z += we * e0.z;  c0.w += we * e0.w;
        c1.x += we * e1.x;  c1.y += we * e1.y;  c1.z += we * e1.z;  c1.w += we * e1.w;
    }
    float inv = 1.0f / den;
    c0.x *= inv; c0.y *= inv; c0.z *= inv; c0.w *= inv;
    c1.x *= inv; c1.y *= inv; c1.z *= inv; c1.w *= inv;

    size_t ab = (size_t)w * 1024;
    split_store4_nt(Ah + ab +       4 * lane, Al + ab +       4 * lane, n0);
    split_store4_nt(Ah + ab + 256 + 4 * lane, Al + ab + 256 + 4 * lane, n1);
    split_store4_nt(Ah + ab + 512 + 4 * lane, Al + ab + 512 + 4 * lane, c0);
    split_store4_nt(Ah + ab + 768 + 4 * lane, Al + ab + 768 + 4 * lane, c1);

    // prp slice of prop-A panel (written once per (i,b) by h==2/h==4)
    if (h == 2 || h == 4) {
        int pid = inputs_prop[((b * 2 + i) * 3) * 32];
        size_t pr = (size_t)(i * 4096 + b) * 1152;
        float4 p0 = emb4[(size_t)pid * 128 + lane];
        float4 p1 = emb4[(size_t)pid * 128 + 64 + lane];
        split_store4_nt(Aph + pr + 600 + 4 * lane, Apl + pr + 600 + 4 * lane, p0);
        split_store4_nt(Aph + pr + 856 + 4 * lane, Apl + pr + 856 + 4 * lane, p1);
        if (lane < 10) {   // zero-fill K pad [1112,1152)
            u16x4 z = (u16x4){0, 0, 0, 0};
            __builtin_nontemporal_store(z, (u16x4*)&Aph[pr + 1112 + 4 * lane]);
            __builtin_nontemporal_store(z, (u16x4*)&Apl[pr + 1112 + 4 * lane]);
        }
    }
}

// =============================================================
// Kernel B: pre-split weights to bf16 hi/lo with padding.
// =============================================================
__global__ __launch_bounds__(256) void bsplit_kernel(
    const float* __restrict__ W_out,   // (300,1024)
    const float* __restrict__ W_prop,  // (300,1112)
    unsigned short* __restrict__ Bh,  unsigned short* __restrict__ Bl,   // (320,1024)
    unsigned short* __restrict__ Bph, unsigned short* __restrict__ Bpl)  // (320,1152)
{
    int id = blockIdx.x * 256 + threadIdx.x;
    const int NB1 = 320 * 1024;
    if (id < NB1) {
        int n = id >> 10, k = id & 1023;
        float x = (n < 300) ? W_out[n * 1024 + k] : 0.0f;
        unsigned short h, l; split2(x, h, l);
        Bh[id] = h; Bl[id] = l;
    } else {
        int id2 = id - NB1;
        if (id2 < 320 * 1152) {
            int n = id2 / 1152, k = id2 - n * 1152;
            float x = (n < 300 && k < 1112) ? W_prop[n * 1112 + k] : 0.0f;
            unsigned short h, l; split2(x, h, l);
            Bph[id2] = h; Bpl[id2] = l;
        }
    }
}

// =============================================================
// Split-bf16 MFMA GEMM: C[M,320] = A[M,K] * B[320,K]^T (+bias)
// BM = MF*32, BN=64, BK=64; 4 waves (2x2); wave tile MF*16 x 32.
// EPI=0: head (writes fp32 ent rows + bf16 dom/rng into prop-A)
// EPI=1: prop (writes fp32 prop_out)
// =============================================================
template<int MF, int KTOT, int NSTEP, int EPI>
__global__ __launch_bounds__(256) void gemm_kernel(
    const unsigned short* __restrict__ Agh, const unsigned short* __restrict__ Agl,
    const unsigned short* __restrict__ Bgh, const unsigned short* __restrict__ Bgl,
    const float* __restrict__ bias,
    float* __restrict__ outf,
    unsigned short* __restrict__ Aph, unsigned short* __restrict__ Apl)
{
    constexpr int BM = MF * 32;
    __shared__ unsigned short Ash[BM * 64], Asl[BM * 64];
    __shared__ unsigned short Bsh[64 * 64], Bsl[64 * 64];

    int t = threadIdx.x, lane = t & 63, wid = t >> 6;
    int wm = wid >> 1, wn = wid & 1;
    int m0 = blockIdx.y * BM, n0 = blockIdx.x * 64;

    f32x4 acc[MF][2];
    #pragma unroll
    for (int mf = 0; mf < MF; ++mf)
        #pragma unroll
        for (int nf = 0; nf < 2; ++nf)
            acc[mf][nf] = (f32x4){0.f, 0.f, 0.f, 0.f};

    constexpr int nA  = MF * 4;            // global_load_lds instrs per A buffer
    constexpr int PER = (2 * nA + 16) / 4; // per wave
    int rowq = lane >> 3, cq = lane & 7;

    for (int step = 0; step < NSTEP; ++step) {
        int k0 = step * 64;
        #pragma unroll
        for (int qq = 0; qq < PER; ++qq) {
            int q = wid * PER + qq;
            const unsigned short* src; unsigned short* dst; int j; size_t grow;
            if (q < nA)              { j = q;            src = Agh; dst = Ash; grow = (size_t)m0; }
            else if (q < 2 * nA)     { j = q - nA;       src = Agl; dst = Asl; grow = (size_t)m0; }
            else if (q < 2 * nA + 8) { j = q - 2 * nA;   src = Bgh; dst = Bsh; grow = (size_t)n0; }
            else                     { j = q - 2 * nA - 8; src = Bgl; dst = Bsl; grow = (size_t)n0; }
            size_t ge = (grow + (size_t)(j * 8 + rowq)) * KTOT + k0 + cq * 8;
            gload16(src + ge, dst + j * 512);
        }
        __syncthreads();   // drains vmcnt + barrier (compiler-inserted waitcnt)

        #pragma unroll
        for (int s = 0; s < 2; ++s) {
            int ko = s * 32 + (lane >> 4) * 8;
            s16x8 ah[MF], al[MF], bh[2], bl[2];
            #pragma unroll
            for (int mf = 0; mf < MF; ++mf) {
                int r = (wm * MF + mf) * 16 + (lane & 15);
                ah[mf] = *reinterpret_cast<const s16x8*>(&Ash[r * 64 + ko]);
                al[mf] = *reinterpret_cast<const s16x8*>(&Asl[r * 64 + ko]);
            }
            #pragma unroll
            for (int nf = 0; nf < 2; ++nf) {
                int r = (wn * 2 + nf) * 16 + (lane & 15);
                bh[nf] = *reinterpret_cast<const s16x8*>(&Bsh[r * 64 + ko]);
                bl[nf] = *reinterpret_cast<const s16x8*>(&Bsl[r * 64 + ko]);
            }
            #pragma unroll
            for (int mf = 0; mf < MF; ++mf)
                #pragma unroll
                for (int nf = 0; nf < 2; ++nf) {
                    acc[mf][nf] = __builtin_amdgcn_mfma_f32_16x16x32_bf16(ah[mf], bh[nf], acc[mf][nf], 0, 0, 0);
                    acc[mf][nf] = __builtin_amdgcn_mfma_f32_16x16x32_bf16(ah[mf], bl[nf], acc[mf][nf], 0, 0, 0);
                    acc[mf][nf] = __builtin_amdgcn_mfma_f32_16x16x32_bf16(al[mf], bh[nf], acc[mf][nf], 0, 0, 0);
                }
        }
        __syncthreads();
    }

    // epilogue: C/D layout col = lane&15, row = (lane>>4)*4 + reg
    #pragma unroll
    for (int mf = 0; mf < MF; ++mf)
        #pragma unroll
        for (int nf = 0; nf < 2; ++nf) {
            int n = n0 + wn * 32 + nf * 16 + (lane & 15);
            if (n >= 300) continue;
            int rowbase = m0 + wm * MF * 16 + mf * 16 + ((lane >> 4) << 2);
            float bv = bias[n];
            #pragma unroll
            for (int r = 0; r < 4; ++r) {
                float val = acc[mf][nf][r] + bv;
                int m = rowbase + r;
                if (EPI == 0) {
                    int h = m >> 12;   // block-uniform
                    if (h < 2) {
                        outf[(size_t)m * 300 + n] = val;
                    } else {
                        unsigned short hh, ll; split2(val, hh, ll);
                        int i = (h - 2) >> 1;
                        int col = ((h - 2) & 1) ? 300 + n : n;
                        size_t ar = (size_t)(i * 4096 + (m & 4095)) * 1152 + col;
                        Aph[ar] = hh; Apl[ar] = ll;
                    }
                } else {
                    outf[(size_t)m * 300 + n] = val;
                }
            }
        }
}

// =============================================================
// Kernel D: cosines -> d_out[0:4096]=x_ent, [4096:8192]=x_prop
// =============================================================
__global__ __launch_bounds__(256) void cosine_kernel(
    const float* __restrict__ head_out,  // (8192,300) ent heads
    const float* __restrict__ prop_out,  // (8192,300)
    float* __restrict__ out)             // (8192,)
{
    int w    = blockIdx.x * 4 + (threadIdx.x >> 6);
    int lane = threadIdx.x & 63;
    const float *a, *b;
    if (w < 4096) {
        a = head_out + (size_t)w * 300;
        b = head_out + (size_t)(4096 + w) * 300;
    } else {
        int b2 = w - 4096;
        a = prop_out + (size_t)b2 * 300;
        b = prop_out + (size_t)(4096 + b2) * 300;
    }
    float ab = 0.f, aa = 0.f, bb = 0.f;
    for (int tt = lane; tt < 300; tt += 64) {
        float av = a[tt], bv = b[tt];
        ab += av * bv; aa += av * av; bb += bv * bv;
    }
    #pragma unroll
    for (int d = 1; d < 64; d <<= 1) {
        ab += __shfl_xor(ab, d);
        aa += __shfl_xor(aa, d);
        bb += __shfl_xor(bb, d);
    }
    if (lane == 0) {
        float na = fmaxf(sqrtf(aa), 1e-8f);
        float nb = fmaxf(sqrtf(bb), 1e-8f);
        out[w] = ab / (na * nb);
    }
}

extern "C" void kernel_launch(void* const* d_in, const int* in_sizes, int n_in,
                              void* d_out, int out_size, void* d_ws, size_t ws_size,
                              hipStream_t stream) {
    const int*   inputs      = (const int*)d_in[0];
    const int*   inputs_prop = (const int*)d_in[1];
    const float* emb         = (const float*)d_in[2];
    const float* W_out       = (const float*)d_in[3];
    const float* b_out       = (const float*)d_in[4];
    const float* v           = (const float*)d_in[5];
    const float* W_prop      = (const float*)d_in[6];
    const float* b_prop      = (const float*)d_in[7];
    float* out = (float*)d_out;

    char* ws = (char*)d_ws;
    unsigned short* Ah  = (unsigned short*)(ws + AH_OFF);
    unsigned short* Al  = (unsigned short*)(ws + AL_OFF);
    unsigned short* Aph = (unsigned short*)(ws + APH_OFF);
    unsigned short* Apl = (unsigned short*)(ws + APL_OFF);
    unsigned short* Bh  = (unsigned short*)(ws + BH_OFF);
    unsigned short* Bl  = (unsigned short*)(ws + BL_OFF);
    unsigned short* Bph = (unsigned short*)(ws + BPH_OFF);
    unsigned short* Bpl = (unsigned short*)(ws + BPL_OFF);
    float* head_out = (float*)(ws + HEAD_OFF);
    float* prop_out = (float*)(ws + PROP_OFF);

    attend_kernel<<<6144, 256, 0, stream>>>(inputs, inputs_prop, emb, v, Ah, Al, Aph, Apl);
    bsplit_kernel<<<2720, 256, 0, stream>>>(W_out, W_prop, Bh, Bl, Bph, Bpl);
    gemm_kernel<4, 1024, 16, 0><<<dim3(5, 192), 256, 0, stream>>>(Ah, Al, Bh, Bl, b_out, head_out, Aph, Apl);
    gemm_kernel<2, 1152, 18, 1><<<dim3(5, 128), 256, 0, stream>>>(Aph, Apl, Bph, Bpl, b_prop, prop_out, nullptr, nullptr);
    cosine_kernel<<<2048, 256, 0, stream>>>(head_out, prop_out, out);
}

// Round 5
// 240.779 us; speedup vs baseline: 1.6989x; 1.6989x over previous
//
#include <hip/hip_runtime.h>

typedef _Float16 f16x8 __attribute__((ext_vector_type(8)));
typedef _Float16 f16x4 __attribute__((ext_vector_type(4)));
typedef float    f32x4 __attribute__((ext_vector_type(4)));

// ---------------- workspace layout (bytes) ----------------
// embh : 100000*512 f16 = 102,400,000
// ctxh : 24576*512  f16 =  25,165,824
// Aph  : 8192*640   f16 =  10,485,760   (prop A: [dom|rng|pad40]; prp gathered)
// Wh   : 320*1024   f16 =     655,360
// Wph  : 320*1152   f16 =     737,280   ([W0..599 | 0x40 | W600..1111])
// head : 8192*300   f32 =   9,830,400
// prop : 8192*300   f32 =   9,830,400
// nidx : 24576 i32, pidx : 8192 i32
#define EMBH_OFF  0ULL
#define CTXH_OFF  102400000ULL
#define APH_OFF   127565824ULL
#define WH_OFF    138051584ULL
#define WPH_OFF   138706944ULL
#define HEAD_OFF  139444224ULL
#define PROP_OFF  149274624ULL
#define NIDX_OFF  159105024ULL
#define PIDX_OFF  159203328ULL   // total 159,236,096 (< round-2's 160.9MB, known to fit)

__device__ __forceinline__ void gload16h(const _Float16* g, _Float16* l) {
    __builtin_amdgcn_global_load_lds(
        (const __attribute__((address_space(1))) unsigned int*)g,
        (__attribute__((address_space(3))) unsigned int*)l, 16, 0, 0);
}

// =============================================================
// Kernel 0: fp32 -> fp16 conversion (emb, W_out, W_prop w/ pad+reorder)
// =============================================================
__global__ __launch_bounds__(256) void conv_kernel(
    const float* __restrict__ emb, const float* __restrict__ W_out,
    const float* __restrict__ W_prop,
    _Float16* __restrict__ embh, _Float16* __restrict__ Wh, _Float16* __restrict__ Wph)
{
    const int N_EMB4 = 12800000;       // 100000*512/4
    const int N_WH4  = 81920;          // 320*1024/4
    const int N_WPH4 = 92160;          // 320*1152/4
    int stride = gridDim.x * 256;
    for (int id = blockIdx.x * 256 + threadIdx.x; id < N_EMB4 + N_WH4 + N_WPH4; id += stride) {
        float4 f; _Float16* dst;
        if (id < N_EMB4) {
            f = ((const float4*)emb)[id];
            dst = embh + (size_t)id * 4;
        } else if (id < N_EMB4 + N_WH4) {
            int id2 = id - N_EMB4;
            int n = id2 >> 8, c4 = id2 & 255;
            f = (n < 300) ? ((const float4*)W_out)[n * 256 + c4] : make_float4(0.f,0.f,0.f,0.f);
            dst = Wh + (size_t)id2 * 4;
        } else {
            int id3 = id - N_EMB4 - N_WH4;
            int n = id3 / 288, c4 = id3 - n * 288;
            if (n >= 300 || (c4 >= 150 && c4 < 160)) f = make_float4(0.f,0.f,0.f,0.f);
            else if (c4 < 150) f = ((const float4*)W_prop)[n * 278 + c4];       // cols 0..599
            else               f = ((const float4*)W_prop)[n * 278 + c4 - 10];  // cols 640.. -> src 600..
            dst = Wph + (size_t)id3 * 4;
        }
        f16x4 h = { (_Float16)f.x, (_Float16)f.y, (_Float16)f.z, (_Float16)f.w };
        *(f16x4*)dst = h;
    }
}

// =============================================================
// Kernel A: gather + online-softmax attention (fp16 table).
// One wave per (h,b); lane holds 8 contiguous elems (16B) of each row.
// Writes: ctxh (fp16), nidx, pidx, Aph pad cols [600,640).
// =============================================================
__global__ __launch_bounds__(256) void attend_kernel(
    const int* __restrict__ inputs,        // (4096,2,32)
    const int* __restrict__ inputs_prop,   // (4096,2,3,32)
    const _Float16* __restrict__ embh,     // (100000,512) f16
    const float* __restrict__ v,           // (31,)
    _Float16* __restrict__ ctxh,           // (24576,512) f16
    int* __restrict__ nidx, int* __restrict__ pidx,
    _Float16* __restrict__ Aph)            // (8192,640) f16
{
    int w    = blockIdx.x * 4 + (threadIdx.x >> 6);
    int lane = threadIdx.x & 63;
    int h = w >> 12;         // 0..5
    int b = w & 4095;

    int base, i = 0;
    const int* ip;
    if (h < 2) { base = (b * 2 + h) * 32; ip = inputs; }
    else {
        i = (h - 2) >> 1;
        int s = 1 + ((h - 2) & 1);
        base = ((b * 2 + i) * 3 + s) * 32;
        ip = inputs_prop;
    }

    int myidx = 0;
    if (lane < 32) myidx = ip[base + lane];
    int idx0 = __shfl(myidx, 0);
    if (lane == 0) {
        nidx[w] = idx0;
        if (h == 2 || h == 4) pidx[i * 4096 + b] = inputs_prop[((b * 2 + i) * 3) * 32];
    }

    const f16x8* e8 = (const f16x8*)embh;
    f16x8 n8 = e8[(size_t)idx0 * 64 + lane];
    float nf[8];
    #pragma unroll
    for (int q = 0; q < 8; ++q) nf[q] = (float)n8[q];

    // 4-deep pipeline (one 16B load per row per lane now)
    f16x8 pe[4];
    #pragma unroll
    for (int j = 1; j <= 4; ++j) {
        int ij = __shfl(myidx, j);
        pe[(j - 1) & 3] = e8[(size_t)ij * 64 + lane];
    }

    float m = -3.0e38f, den = 0.0f;
    float c[8] = {0.f,0.f,0.f,0.f,0.f,0.f,0.f,0.f};

    #pragma unroll
    for (int j = 1; j < 32; ++j) {
        const int slot = (j - 1) & 3;
        f16x8 ev = pe[slot];
        if (j + 4 < 32) {
            int ijn = __shfl(myidx, j + 4);
            pe[slot] = e8[(size_t)ijn * 64 + lane];
        }
        float ef[8];
        #pragma unroll
        for (int q = 0; q < 8; ++q) ef[q] = (float)ev[q];
        float p = ef[0]*nf[0] + ef[1]*nf[1] + ef[2]*nf[2] + ef[3]*nf[3]
                + ef[4]*nf[4] + ef[5]*nf[5] + ef[6]*nf[6] + ef[7]*nf[7];
        #pragma unroll
        for (int d = 1; d < 64; d <<= 1) p += __shfl_xor(p, d);

        float s = (p != 0.0f) ? p : -9999.0f;   // mask: scores==0 -> -NEG
        if (s - m > 8.0f) {                     // rare, wave-uniform rescale (T13)
            float scale = __expf(m - s);
            den *= scale;
            #pragma unroll
            for (int q = 0; q < 8; ++q) c[q] *= scale;
            m = s;
        }
        float e = __expf(s - m);
        den += e;
        float we = v[j - 1] * e;
        #pragma unroll
        for (int q = 0; q < 8; ++q) c[q] += we * ef[q];
    }
    float inv = 1.0f / den;
    f16x8 co;
    #pragma unroll
    for (int q = 0; q < 8; ++q) co[q] = (_Float16)(c[q] * inv);
    __builtin_nontemporal_store(co, (f16x8*)(ctxh + (size_t)w * 512 + lane * 8));

    // zero-fill Aph pad cols [600,640) once per prop row
    if ((h == 2 || h == 4) && lane < 5) {
        f16x8 z = {};
        __builtin_nontemporal_store(z, (f16x8*)(Aph + (size_t)(i * 4096 + b) * 640 + 600 + lane * 8));
    }
}

// =============================================================
// Kernel B: head GEMM  Y[24576,320] = [node|ctx](f16) @ Wh^T + b
// node gathered from embh via nidx; ctx from ctxh. BM=128,BN=64,BK=64.
// XOR-swizzled LDS (T2, rule #21: inverse-swizzled global source).
// ent rows -> fp32 head_out; dom/rng -> f16 into Aph cols [0,600).
// =============================================================
__global__ __launch_bounds__(256) void gemm_head_kernel(
    const _Float16* __restrict__ embh, const _Float16* __restrict__ ctxh,
    const int* __restrict__ nidx, const _Float16* __restrict__ Wh,
    const float* __restrict__ bias, float* __restrict__ outf,
    _Float16* __restrict__ Aph)
{
    __shared__ _Float16 Ash[128 * 64], Bsh[64 * 64];
    __shared__ int sN[128];

    int t = threadIdx.x, lane = t & 63, wid = t >> 6;
    int wm = wid >> 1, wn = wid & 1;
    int m0 = blockIdx.y * 128, n0 = blockIdx.x * 64;
    if (t < 128) sN[t] = nidx[m0 + t];
    __syncthreads();

    f32x4 acc[4][2];
    #pragma unroll
    for (int mf = 0; mf < 4; ++mf)
        #pragma unroll
        for (int nf = 0; nf < 2; ++nf) acc[mf][nf] = (f32x4){0.f,0.f,0.f,0.f};

    int rowq = lane >> 3, cq = lane & 7;
    int cqs = cq ^ rowq;                 // inverse swizzle on global source

    for (int k0 = 0; k0 < 1024; k0 += 64) {
        #pragma unroll
        for (int qq = 0; qq < 6; ++qq) {
            int q = wid * 6 + qq;
            if (q < 16) {                // A tile: 128 rows x 64 halves
                int row = q * 8 + rowq;
                if (k0 < 512) gload16h(embh + (size_t)sN[row] * 512 + k0 + cqs * 8, Ash + q * 512);
                else          gload16h(ctxh + (size_t)(m0 + row) * 512 + (k0 - 512) + cqs * 8, Ash + q * 512);
            } else {                     // B tile: 64 rows x 64 halves
                int j = q - 16, row = j * 8 + rowq;
                gload16h(Wh + (size_t)(n0 + row) * 1024 + k0 + cqs * 8, Bsh + j * 512);
            }
        }
        __syncthreads();

        int l15 = lane & 15, hi = lane >> 4, l7 = lane & 7;
        #pragma unroll
        for (int s = 0; s < 2; ++s) {
            int sw = ((s * 4 + hi) ^ l7) * 8;   // swizzled 16B-chunk within row
            f16x8 a[4], bb[2];
            #pragma unroll
            for (int mf = 0; mf < 4; ++mf)
                a[mf] = *(const f16x8*)&Ash[((wm * 4 + mf) * 16 + l15) * 64 + sw];
            #pragma unroll
            for (int nf = 0; nf < 2; ++nf)
                bb[nf] = *(const f16x8*)&Bsh[((wn * 2 + nf) * 16 + l15) * 64 + sw];
            #pragma unroll
            for (int mf = 0; mf < 4; ++mf)
                #pragma unroll
                for (int nf = 0; nf < 2; ++nf)
                    acc[mf][nf] = __builtin_amdgcn_mfma_f32_16x16x32_f16(a[mf], bb[nf], acc[mf][nf], 0, 0, 0);
        }
        __syncthreads();
    }

    // epilogue: C/D layout col = lane&15, row = (lane>>4)*4 + reg
    #pragma unroll
    for (int mf = 0; mf < 4; ++mf)
        #pragma unroll
        for (int nf = 0; nf < 2; ++nf) {
            int n = n0 + wn * 32 + nf * 16 + (lane & 15);
            if (n >= 300) continue;
            int rowbase = m0 + (wm * 4 + mf) * 16 + ((lane >> 4) << 2);
            float bv = bias[n];
            #pragma unroll
            for (int r = 0; r < 4; ++r) {
                float val = acc[mf][nf][r] + bv;
                int mm = rowbase + r;
                int h = mm >> 12;        // block-uniform
                if (h < 2) {
                    outf[(size_t)mm * 300 + n] = val;
                } else {
                    int i = (h - 2) >> 1;
                    int col = ((h - 2) & 1) ? 300 + n : n;
                    Aph[(size_t)(i * 4096 + (mm & 4095)) * 640 + col] = (_Float16)val;
                }
            }
        }
}

// =============================================================
// Kernel C: prop GEMM  P[8192,320] = [dom|rng|pad|prp](f16) @ Wph^T + b
// cols [0,640) from Aph; [640,1152) gathered from embh via pidx.
// BM=64, BN=64, BK=64, K=1152.
// =============================================================
__global__ __launch_bounds__(256) void gemm_prop_kernel(
    const _Float16* __restrict__ Aph, const int* __restrict__ pidx,
    const _Float16* __restrict__ embh, const _Float16* __restrict__ Wph,
    const float* __restrict__ bias, float* __restrict__ outf)
{
    __shared__ _Float16 Ash[64 * 64], Bsh[64 * 64];
    __shared__ int sPid[64];

    int t = threadIdx.x, lane = t & 63, wid = t >> 6;
    int wm = wid >> 1, wn = wid & 1;
    int m0 = blockIdx.y * 64, n0 = blockIdx.x * 64;
    if (t < 64) {
        int mm = m0 + t;
        sPid[t] = pidx[(mm >> 12) * 4096 + (mm & 4095)];
    }
    __syncthreads();

    f32x4 acc[2][2];
    #pragma unroll
    for (int mf = 0; mf < 2; ++mf)
        #pragma unroll
        for (int nf = 0; nf < 2; ++nf) acc[mf][nf] = (f32x4){0.f,0.f,0.f,0.f};

    int rowq = lane >> 3, cq = lane & 7;
    int cqs = cq ^ rowq;

    for (int k0 = 0; k0 < 1152; k0 += 64) {
        #pragma unroll
        for (int qq = 0; qq < 4; ++qq) {
            int q = wid * 4 + qq;
            if (q < 8) {                 // A tile: 64 rows
                int row = q * 8 + rowq;
                if (k0 < 640) gload16h(Aph + (size_t)(m0 + row) * 640 + k0 + cqs * 8, Ash + q * 512);
                else          gload16h(embh + (size_t)sPid[row] * 512 + (k0 - 640) + cqs * 8, Ash + q * 512);
            } else {
                int j = q - 8, row = j * 8 + rowq;
                gload16h(Wph + (size_t)(n0 + row) * 1152 + k0 + cqs * 8, Bsh + j * 512);
            }
        }
        __syncthreads();

        int l15 = lane & 15, hi = lane >> 4, l7 = lane & 7;
        #pragma unroll
        for (int s = 0; s < 2; ++s) {
            int sw = ((s * 4 + hi) ^ l7) * 8;
            f16x8 a[2], bb[2];
            #pragma unroll
            for (int mf = 0; mf < 2; ++mf)
                a[mf] = *(const f16x8*)&Ash[((wm * 2 + mf) * 16 + l15) * 64 + sw];
            #pragma unroll
            for (int nf = 0; nf < 2; ++nf)
                bb[nf] = *(const f16x8*)&Bsh[((wn * 2 + nf) * 16 + l15) * 64 + sw];
            #pragma unroll
            for (int mf = 0; mf < 2; ++mf)
                #pragma unroll
                for (int nf = 0; nf < 2; ++nf)
                    acc[mf][nf] = __builtin_amdgcn_mfma_f32_16x16x32_f16(a[mf], bb[nf], acc[mf][nf], 0, 0, 0);
        }
        __syncthreads();
    }

    #pragma unroll
    for (int mf = 0; mf < 2; ++mf)
        #pragma unroll
        for (int nf = 0; nf < 2; ++nf) {
            int n = n0 + wn * 32 + nf * 16 + (lane & 15);
            if (n >= 300) continue;
            int rowbase = m0 + (wm * 2 + mf) * 16 + ((lane >> 4) << 2);
            float bv = bias[n];
            #pragma unroll
            for (int r = 0; r < 4; ++r)
                outf[(size_t)(rowbase + r) * 300 + n] = acc[mf][nf][r] + bv;
        }
}

// =============================================================
// Kernel D: cosines -> d_out[0:4096]=x_ent, [4096:8192]=x_prop
// =============================================================
__global__ __launch_bounds__(256) void cosine_kernel(
    const float* __restrict__ head_out,  // (8192,300) ent heads
    const float* __restrict__ prop_out,  // (8192,300)
    float* __restrict__ out)             // (8192,)
{
    int w    = blockIdx.x * 4 + (threadIdx.x >> 6);
    int lane = threadIdx.x & 63;
    const float *a, *b;
    if (w < 4096) {
        a = head_out + (size_t)w * 300;
        b = head_out + (size_t)(4096 + w) * 300;
    } else {
        int b2 = w - 4096;
        a = prop_out + (size_t)b2 * 300;
        b = prop_out + (size_t)(4096 + b2) * 300;
    }
    float ab = 0.f, aa = 0.f, bb = 0.f;
    for (int tt = lane; tt < 300; tt += 64) {
        float av = a[tt], bv = b[tt];
        ab += av * bv; aa += av * av; bb += bv * bv;
    }
    #pragma unroll
    for (int d = 1; d < 64; d <<= 1) {
        ab += __shfl_xor(ab, d);
        aa += __shfl_xor(aa, d);
        bb += __shfl_xor(bb, d);
    }
    if (lane == 0) {
        float na = fmaxf(sqrtf(aa), 1e-8f);
        float nb = fmaxf(sqrtf(bb), 1e-8f);
        out[w] = ab / (na * nb);
    }
}

extern "C" void kernel_launch(void* const* d_in, const int* in_sizes, int n_in,
                              void* d_out, int out_size, void* d_ws, size_t ws_size,
                              hipStream_t stream) {
    const int*   inputs      = (const int*)d_in[0];
    const int*   inputs_prop = (const int*)d_in[1];
    const float* emb         = (const float*)d_in[2];
    const float* W_out       = (const float*)d_in[3];
    const float* b_out       = (const float*)d_in[4];
    const float* v           = (const float*)d_in[5];
    const float* W_prop      = (const float*)d_in[6];
    const float* b_prop      = (const float*)d_in[7];
    float* out = (float*)d_out;

    char* ws = (char*)d_ws;
    _Float16* embh = (_Float16*)(ws + EMBH_OFF);
    _Float16* ctxh = (_Float16*)(ws + CTXH_OFF);
    _Float16* Aph  = (_Float16*)(ws + APH_OFF);
    _Float16* Wh   = (_Float16*)(ws + WH_OFF);
    _Float16* Wph  = (_Float16*)(ws + WPH_OFF);
    float* head_out = (float*)(ws + HEAD_OFF);
    float* prop_out = (float*)(ws + PROP_OFF);
    int*   nidx     = (int*)(ws + NIDX_OFF);
    int*   pidx     = (int*)(ws + PIDX_OFF);

    conv_kernel<<<8192, 256, 0, stream>>>(emb, W_out, W_prop, embh, Wh, Wph);
    attend_kernel<<<6144, 256, 0, stream>>>(inputs, inputs_prop, embh, v, ctxh, nidx, pidx, Aph);
    gemm_head_kernel<<<dim3(5, 192), 256, 0, stream>>>(embh, ctxh, nidx, Wh, b_out, head_out, Aph);
    gemm_prop_kernel<<<dim3(5, 128), 256, 0, stream>>>(Aph, pidx, embh, Wph, b_prop, prop_out);
    cosine_kernel<<<2048, 256, 0, stream>>>(head_out, prop_out, out);
}